// Round 1
// baseline (254.576 us; speedup 1.0000x reference)
//
#include <hip/hip_runtime.h>

// Problem constants
#define BATCH 32
#define NOBJ  64
#define SIZE  256
#define PADK  264   // LDS row stride in halfs (+8 pad to break 512B bank stride)

typedef _Float16 f16x8 __attribute__((ext_vector_type(8)));
typedef float    f32x4 __attribute__((ext_vector_type(4)));

// ---------------------------------------------------------------------------
// Kernel 0: transpose + pad g-weights to f16  Wt[layer][n=256][k=256]
//   Wt[l][n][k] = (k < fan_in_l) ? W_l[k][n] : 0        (fan_in_0 = 194)
// ---------------------------------------------------------------------------
__global__ __launch_bounds__(256) void prep_weights(
    const float* __restrict__ g1w, const float* __restrict__ g2w,
    const float* __restrict__ g3w, const float* __restrict__ g4w,
    _Float16* __restrict__ wt) {
  int id  = blockIdx.x * 256 + threadIdx.x;   // 4*256*256 total
  int l   = id >> 16;
  int rem = id & 65535;
  int n   = rem >> 8;
  int k   = rem & 255;
  const float* src = (l == 0) ? g1w : (l == 1) ? g2w : (l == 2) ? g3w : g4w;
  int fin = (l == 0) ? 194 : 256;
  float v = (k < fin) ? src[k * 256 + n] : 0.0f;
  wt[id] = (_Float16)v;
}

// ---------------------------------------------------------------------------
// Kernel 1: fused g-MLP (4 layers) + sum-pool over j for one (b, i).
// Block = 256 threads (4 waves). M = 64 rows (j), N = 256 cols, K = 256.
// Each wave owns a 64-col slice; 16x16x32 f16 MFMA; acc fp32 in VGPRs.
// ---------------------------------------------------------------------------
__global__ __launch_bounds__(256, 3) void g_mlp_pool(
    const float* __restrict__ x_aux,          // [B, 64, 128] fp32
    const _Float16* __restrict__ wt,          // [4][256][256] f16
    const float* __restrict__ g1b, const float* __restrict__ g2b,
    const float* __restrict__ g3b, const float* __restrict__ g4b,
    float* __restrict__ partial) {            // [B*64][256] fp32
  __shared__ _Float16 As[64][PADK];

  const int blk = blockIdx.x;
  const int b   = blk >> 6;
  const int i   = blk & 63;
  const int tid = threadIdx.x;

  // ---- build layer-1 input tile: row j, cols:
  //   [0,64)   = x_aux[b][j][0:64]
  //   64       = j
  //   [65,193) = x_aux[b][i][0:128]
  //   193      = i
  //   [194,256)= 0
  {
    const int row = tid & 63;          // = lane -> wave-uniform seg below
    const int seg = tid >> 6;          // 0..3, uniform within a wave
    const float* xr = x_aux + (size_t)(b * NOBJ + row) * 128;
    const float* xi = x_aux + (size_t)(b * NOBJ + i)   * 128;
    for (int c0 = 0; c0 < 64; ++c0) {
      int c = seg * 64 + c0;
      float v;
      if (c < 64)        v = xr[c];
      else if (c == 64)  v = (float)row;
      else if (c < 193)  v = xi[c - 65];
      else if (c == 193) v = (float)i;
      else               v = 0.0f;
      As[row][c] = (_Float16)v;
    }
  }
  __syncthreads();

  const int lane = tid & 63;
  const int wave = tid >> 6;
  const int l15  = lane & 15;
  const int quad = lane >> 4;
  const int n0   = wave * 64;          // this wave's 64-col slice

  for (int layer = 0; layer < 4; ++layer) {
    const _Float16* w = wt + (size_t)layer * 65536;
    const float* bias = (layer == 0) ? g1b : (layer == 1) ? g2b
                      : (layer == 2) ? g3b : g4b;

    f32x4 acc[4][4];
#pragma unroll
    for (int mi = 0; mi < 4; ++mi)
#pragma unroll
      for (int ni = 0; ni < 4; ++ni)
        acc[mi][ni] = (f32x4){0.f, 0.f, 0.f, 0.f};

#pragma unroll 2
    for (int k0 = 0; k0 < 256; k0 += 32) {
      const int ka = k0 + quad * 8;
      f16x8 a[4], bf[4];
#pragma unroll
      for (int mi = 0; mi < 4; ++mi)
        a[mi] = *(const f16x8*)&As[mi * 16 + l15][ka];
#pragma unroll
      for (int ni = 0; ni < 4; ++ni)
        bf[ni] = *(const f16x8*)(w + (size_t)(n0 + ni * 16 + l15) * 256 + ka);
#pragma unroll
      for (int ni = 0; ni < 4; ++ni)
#pragma unroll
        for (int mi = 0; mi < 4; ++mi)
          acc[mi][ni] = __builtin_amdgcn_mfma_f32_16x16x32_f16(
              a[mi], bf[ni], acc[mi][ni], 0, 0, 0);
    }

    float bv[4];
#pragma unroll
    for (int ni = 0; ni < 4; ++ni) bv[ni] = bias[n0 + ni * 16 + l15];

    if (layer < 3) {
      __syncthreads();   // everyone done reading As for this layer
      // C/D layout: row = quad*4 + r (+16*mi), col = l15 (+16*ni + n0)
#pragma unroll
      for (int mi = 0; mi < 4; ++mi)
#pragma unroll
        for (int ni = 0; ni < 4; ++ni)
#pragma unroll
          for (int r = 0; r < 4; ++r) {
            float v = acc[mi][ni][r] + bv[ni];
            As[mi * 16 + quad * 4 + r][n0 + ni * 16 + l15] =
                (_Float16)fmaxf(v, 0.f);
          }
      __syncthreads();
    } else {
      // layer 4: bias + relu + pool over all 64 rows
#pragma unroll
      for (int ni = 0; ni < 4; ++ni) {
        float s = 0.f;
#pragma unroll
        for (int mi = 0; mi < 4; ++mi)
#pragma unroll
          for (int r = 0; r < 4; ++r)
            s += fmaxf(acc[mi][ni][r] + bv[ni], 0.f);
        // reduce across the 4 quads (rows are partitioned by quad)
        s += __shfl_xor(s, 16, 64);
        s += __shfl_xor(s, 32, 64);
        if (quad == 0)
          partial[(size_t)(b * NOBJ + i) * 256 + n0 + ni * 16 + l15] = s;
      }
    }
  }
}

// ---------------------------------------------------------------------------
// Kernel 2: reduce partials over i, then f-MLP (fp32, tiny).
// One block per batch, thread n owns output column n.
// ---------------------------------------------------------------------------
__global__ __launch_bounds__(256) void f_mlp(
    const float* __restrict__ partial,
    const float* __restrict__ f1w, const float* __restrict__ f1b,
    const float* __restrict__ f2w, const float* __restrict__ f2b,
    const float* __restrict__ f3w, const float* __restrict__ f3b,
    float* __restrict__ out) {
  __shared__ float xs[256], ys[256];
  const int b = blockIdx.x;
  const int n = threadIdx.x;

  float s = 0.f;
  for (int i = 0; i < NOBJ; ++i)
    s += partial[(size_t)(b * NOBJ + i) * 256 + n];
  xs[n] = s;
  __syncthreads();

  float a = f1b[n];
  for (int k = 0; k < 256; ++k) a += xs[k] * f1w[k * 256 + n];
  ys[n] = fmaxf(a, 0.f);
  __syncthreads();

  a = f2b[n];
  for (int k = 0; k < 256; ++k) a += ys[k] * f2w[k * 256 + n];
  xs[n] = fmaxf(a, 0.f);
  __syncthreads();

  a = f3b[n];
  for (int k = 0; k < 256; ++k) a += xs[k] * f3w[k * 256 + n];
  out[b * 256 + n] = a;
}

// ---------------------------------------------------------------------------
extern "C" void kernel_launch(void* const* d_in, const int* in_sizes, int n_in,
                              void* d_out, int out_size, void* d_ws, size_t ws_size,
                              hipStream_t stream) {
  const float* x_aux = (const float*)d_in[0];
  const float* g1w = (const float*)d_in[1];
  const float* g1b = (const float*)d_in[2];
  const float* g2w = (const float*)d_in[3];
  const float* g2b = (const float*)d_in[4];
  const float* g3w = (const float*)d_in[5];
  const float* g3b = (const float*)d_in[6];
  const float* g4w = (const float*)d_in[7];
  const float* g4b = (const float*)d_in[8];
  const float* f1w = (const float*)d_in[9];
  const float* f1b = (const float*)d_in[10];
  const float* f2w = (const float*)d_in[11];
  const float* f2b = (const float*)d_in[12];
  const float* f3w = (const float*)d_in[13];
  const float* f3b = (const float*)d_in[14];
  float* out = (float*)d_out;

  _Float16* wt = (_Float16*)d_ws;                                   // 512 KB
  float* partial = (float*)((char*)d_ws + 4u * 256u * 256u * 2u);   // 2 MB

  hipLaunchKernelGGL(prep_weights, dim3(1024), dim3(256), 0, stream,
                     g1w, g2w, g3w, g4w, wt);
  hipLaunchKernelGGL(g_mlp_pool, dim3(BATCH * NOBJ), dim3(256), 0, stream,
                     x_aux, wt, g1b, g2b, g3b, g4b, partial);
  hipLaunchKernelGGL(f_mlp, dim3(BATCH), dim3(256), 0, stream,
                     partial, f1w, f1b, f2w, f2b, f3w, f3b, out);
}

// Round 2
// 238.619 us; speedup vs baseline: 1.0669x; 1.0669x over previous
//
#include <hip/hip_runtime.h>

#define BATCH 32
#define NOBJ  64
#define PADK  264   // halfs; row stride 528 B = 33*16 -> 16B-aligned rows

typedef _Float16 f16x4 __attribute__((ext_vector_type(4)));
typedef _Float16 f16x8 __attribute__((ext_vector_type(8)));
typedef float    f32x4 __attribute__((ext_vector_type(4)));
typedef float    f32x16 __attribute__((ext_vector_type(16)));

// ---------------------------------------------------------------------------
// Kernel 0: LDS-tiled transpose+pad of g-weights to f16 Wt[l][n=256][k=256],
// with the layer-1 K order PERMUTED to match the tile-build layout:
//   new k: [0,64)=feats_j (old k), [64,192)=feats_i (old k+1),
//          192=coord j (old 64), 193=coord i (old 193), [194,256)=0.
// Also zeroes the x_g accumulator (32x256 floats).
// Grid: 4 layers * 8 * 8 tiles = 256 blocks x 256 threads.
// ---------------------------------------------------------------------------
__global__ __launch_bounds__(256) void prep_weights(
    const float* __restrict__ g1w, const float* __restrict__ g2w,
    const float* __restrict__ g3w, const float* __restrict__ g4w,
    _Float16* __restrict__ wt, float* __restrict__ xg) {
  __shared__ float tile[32][33];
  const int t = threadIdx.x;
  if (blockIdx.x < 32) xg[blockIdx.x * 256 + t] = 0.0f;

  const int blk = blockIdx.x;
  const int l  = blk >> 6;
  const int kt = (blk >> 3) & 7;
  const int nt = blk & 7;
  const float* src = (l == 0) ? g1w : (l == 1) ? g2w : (l == 2) ? g3w : g4w;

  const int rr = t >> 5;     // 0..7
  const int cc = t & 31;     // 0..31
#pragma unroll
  for (int it = 0; it < 4; ++it) {
    int kl = it * 8 + rr;
    int nk = kt * 32 + kl;     // new k index
    int ok;                    // old k index
    if (l == 0) {
      if (nk < 64)       ok = nk;
      else if (nk < 192) ok = nk + 1;
      else if (nk == 192) ok = 64;
      else if (nk == 193) ok = 193;
      else               ok = -1;
    } else {
      ok = nk;
    }
    float v = (ok >= 0) ? src[(size_t)ok * 256 + nt * 32 + cc] : 0.0f;
    tile[kl][cc] = v;
  }
  __syncthreads();
#pragma unroll
  for (int it = 0; it < 4; ++it) {
    int nl = it * 8 + rr;
    wt[(size_t)l * 65536 + (size_t)(nt * 32 + nl) * 256 + kt * 32 + cc] =
        (_Float16)tile[cc][nl];
  }
}

// ---------------------------------------------------------------------------
// Kernel 1: fused g-MLP (4 layers) + sum-pool for one (b, i).
// Block = 256 thr (4 waves). M=64 (j), N=256, K=256. 32x32x16 f16 MFMA.
// Each wave: 64-col slice = 2x2 tiles of 32x32. Pool -> atomicAdd x_g.
// ---------------------------------------------------------------------------
__global__ __launch_bounds__(256, 4) void g_mlp_pool(
    const float* __restrict__ x_aux,          // [B, 64, 128] fp32
    const _Float16* __restrict__ wt,          // [4][256][256] f16
    const float* __restrict__ g1b, const float* __restrict__ g2b,
    const float* __restrict__ g3b, const float* __restrict__ g4b,
    float* __restrict__ xg) {                 // [B][256] fp32 (pre-zeroed)
  __shared__ _Float16 As[64][PADK];

  const int b = blockIdx.x >> 6;
  const int i = blockIdx.x & 63;
  const int t = threadIdx.x;

  // ---- build layer-1 input tile (vectorized, coalesced) ----
  {
    const float* xb = x_aux + (size_t)b * NOBJ * 128;
    // part 1: cols [0,64) = x_aux[b][row][0:64]; 16 lanes read 256B contig
    {
      const int c4 = t & 15, r0 = t >> 4;
#pragma unroll
      for (int it = 0; it < 4; ++it) {
        int r = it * 16 + r0;
        f32x4 v = *(const f32x4*)(xb + (size_t)r * 128 + c4 * 4);
        f16x4 hh = {(_Float16)v[0], (_Float16)v[1], (_Float16)v[2], (_Float16)v[3]};
        *(f16x4*)&As[r][c4 * 4] = hh;
      }
    }
    // part 2: cols [64,192) = x_aux[b][i][0:128] (block-uniform, L1-hit)
    // part 3: cols [192,256) = zeros, then coords at 192 (=row), 193 (=i)
    {
      const float* xi = xb + (size_t)i * 128;
      const int row = t >> 2, seg = t & 3;
#pragma unroll
      for (int u = 0; u < 4; ++u) {
        int c = seg * 32 + u * 8;
        f32x4 v0 = *(const f32x4*)(xi + c);
        f32x4 v1 = *(const f32x4*)(xi + c + 4);
        f16x8 hh = {(_Float16)v0[0], (_Float16)v0[1], (_Float16)v0[2], (_Float16)v0[3],
                    (_Float16)v1[0], (_Float16)v1[1], (_Float16)v1[2], (_Float16)v1[3]};
        *(f16x8*)&As[row][64 + c] = hh;
      }
      f16x8 z = {};
      *(f16x8*)&As[row][192 + seg * 16]     = z;
      *(f16x8*)&As[row][192 + seg * 16 + 8] = z;
      if (seg == 0) {   // same thread that zeroed cols 192..207 of this row
        As[row][192] = (_Float16)row;
        As[row][193] = (_Float16)i;
      }
    }
  }
  __syncthreads();

  const int lane = t & 63;
  const int wave = t >> 6;
  const int c31  = lane & 31;
  const int h    = lane >> 5;        // 0/1
  const int n0   = wave * 64;
  const float* gb[4] = {g1b, g2b, g3b, g4b};

  for (int layer = 0; layer < 4; ++layer) {
    const _Float16* w = wt + (size_t)layer * 65536;
    const float bv0 = gb[layer][n0 + c31];
    const float bv1 = gb[layer][n0 + 32 + c31];

    f32x16 acc00 = {}, acc01 = {}, acc10 = {}, acc11 = {};

    const _Float16* wr0 = w + (size_t)(n0 + c31) * 256 + h * 8;
    const _Float16* wr1 = wr0 + 32 * 256;
    const _Float16* ar0 = &As[c31][h * 8];
    const _Float16* ar1 = &As[32 + c31][h * 8];

    f16x8 b0 = *(const f16x8*)wr0;
    f16x8 b1 = *(const f16x8*)wr1;
#pragma unroll
    for (int kk = 0; kk < 16; ++kk) {
      f16x8 a0 = *(const f16x8*)(ar0 + kk * 16);
      f16x8 a1 = *(const f16x8*)(ar1 + kk * 16);
      f16x8 nb0 = b0, nb1 = b1;
      if (kk < 15) {
        nb0 = *(const f16x8*)(wr0 + (kk + 1) * 16);
        nb1 = *(const f16x8*)(wr1 + (kk + 1) * 16);
      }
      acc00 = __builtin_amdgcn_mfma_f32_32x32x16_f16(a0, b0, acc00, 0, 0, 0);
      acc10 = __builtin_amdgcn_mfma_f32_32x32x16_f16(a1, b0, acc10, 0, 0, 0);
      acc01 = __builtin_amdgcn_mfma_f32_32x32x16_f16(a0, b1, acc01, 0, 0, 0);
      acc11 = __builtin_amdgcn_mfma_f32_32x32x16_f16(a1, b1, acc11, 0, 0, 0);
      b0 = nb0; b1 = nb1;
    }

    if (layer < 3) {
      __syncthreads();   // all waves done reading As
      // C/D layout: col = lane&31, row = (reg&3) + 8*(reg>>2) + 4*h
      // 64 lanes spread across all 32 banks -> conflict-free b16 writes
#pragma unroll
      for (int g = 0; g < 4; ++g)
#pragma unroll
        for (int r = 0; r < 4; ++r) {
          const int row = g * 8 + h * 4 + r;
          const int reg = g * 4 + r;
          As[row][n0 + c31]           = (_Float16)fmaxf(acc00[reg] + bv0, 0.f);
          As[32 + row][n0 + c31]      = (_Float16)fmaxf(acc10[reg] + bv0, 0.f);
          As[row][n0 + 32 + c31]      = (_Float16)fmaxf(acc01[reg] + bv1, 0.f);
          As[32 + row][n0 + 32 + c31] = (_Float16)fmaxf(acc11[reg] + bv1, 0.f);
        }
      __syncthreads();
    } else {
      // layer 4: bias + relu + pool over all 64 rows -> atomicAdd into x_g
      float s0 = 0.f, s1 = 0.f;
#pragma unroll
      for (int reg = 0; reg < 16; ++reg) {
        s0 += fmaxf(acc00[reg] + bv0, 0.f) + fmaxf(acc10[reg] + bv0, 0.f);
        s1 += fmaxf(acc01[reg] + bv1, 0.f) + fmaxf(acc11[reg] + bv1, 0.f);
      }
      s0 += __shfl_xor(s0, 32, 64);   // combine h=0/h=1 row halves
      s1 += __shfl_xor(s1, 32, 64);
      if (h == 0) {
        atomicAdd(&xg[b * 256 + n0 + c31], s0);
        atomicAdd(&xg[b * 256 + n0 + 32 + c31], s1);
      }
    }
  }
}

// ---------------------------------------------------------------------------
// Kernel 2: f-MLP (fp32, tiny). One block per batch, thread n = column n.
// ---------------------------------------------------------------------------
__global__ __launch_bounds__(256) void f_mlp(
    const float* __restrict__ xg,
    const float* __restrict__ f1w, const float* __restrict__ f1b,
    const float* __restrict__ f2w, const float* __restrict__ f2b,
    const float* __restrict__ f3w, const float* __restrict__ f3b,
    float* __restrict__ out) {
  __shared__ float xs[256], ys[256];
  const int b = blockIdx.x;
  const int n = threadIdx.x;

  xs[n] = xg[b * 256 + n];
  __syncthreads();

  float a = f1b[n];
#pragma unroll 8
  for (int k = 0; k < 256; ++k) a += xs[k] * f1w[k * 256 + n];
  ys[n] = fmaxf(a, 0.f);
  __syncthreads();

  a = f2b[n];
#pragma unroll 8
  for (int k = 0; k < 256; ++k) a += ys[k] * f2w[k * 256 + n];
  xs[n] = fmaxf(a, 0.f);
  __syncthreads();

  a = f3b[n];
#pragma unroll 8
  for (int k = 0; k < 256; ++k) a += xs[k] * f3w[k * 256 + n];
  out[b * 256 + n] = a;
}

// ---------------------------------------------------------------------------
extern "C" void kernel_launch(void* const* d_in, const int* in_sizes, int n_in,
                              void* d_out, int out_size, void* d_ws, size_t ws_size,
                              hipStream_t stream) {
  const float* x_aux = (const float*)d_in[0];
  const float* g1w = (const float*)d_in[1];
  const float* g1b = (const float*)d_in[2];
  const float* g2w = (const float*)d_in[3];
  const float* g2b = (const float*)d_in[4];
  const float* g3w = (const float*)d_in[5];
  const float* g3b = (const float*)d_in[6];
  const float* g4w = (const float*)d_in[7];
  const float* g4b = (const float*)d_in[8];
  const float* f1w = (const float*)d_in[9];
  const float* f1b = (const float*)d_in[10];
  const float* f2w = (const float*)d_in[11];
  const float* f2b = (const float*)d_in[12];
  const float* f3w = (const float*)d_in[13];
  const float* f3b = (const float*)d_in[14];
  float* out = (float*)d_out;

  _Float16* wt = (_Float16*)d_ws;                                  // 512 KB
  float* xg = (float*)((char*)d_ws + 4u * 256u * 256u * 2u);       // 32 KB

  hipLaunchKernelGGL(prep_weights, dim3(256), dim3(256), 0, stream,
                     g1w, g2w, g3w, g4w, wt, xg);
  hipLaunchKernelGGL(g_mlp_pool, dim3(BATCH * NOBJ), dim3(256), 0, stream,
                     x_aux, wt, g1b, g2b, g3b, g4b, xg);
  hipLaunchKernelGGL(f_mlp, dim3(BATCH), dim3(256), 0, stream,
                     xg, f1w, f1b, f2w, f2b, f3w, f3b, out);
}

// Round 3
// 174.087 us; speedup vs baseline: 1.4624x; 1.3707x over previous
//
#include <hip/hip_runtime.h>

#define BATCH 32
#define NOBJ  64
#define PADK  264   // halfs; A-tile row stride 528 B (16B-aligned, banks spread)

typedef _Float16 f16x4 __attribute__((ext_vector_type(4)));
typedef _Float16 f16x8 __attribute__((ext_vector_type(8)));
typedef float    f32x4 __attribute__((ext_vector_type(4)));
typedef float    f32x16 __attribute__((ext_vector_type(16)));

// ---------------------------------------------------------------------------
// Kernel 0: repack g-weights to f16 in MFMA B-FRAGMENT order:
//   wtf[l][ngrp=8][kk=16][lane=64][j=8],  value = W_l[perm_l(k)][n]
//   where n = ngrp*32 + (lane&31), k = kk*16 + (lane>>5)*8 + j.
// Layer-0 K-permutation matches the A-tile build:
//   newk [0,64)=old k (feats_j), [64,192)=old k+1 (feats_i),
//   192=old 64 (coord j), 193=old 193 (coord i), [194,256)=0.
// Grid: 32 blocks (l=blk>>3, ngrp=blk&7) x 256 threads. Also zeroes xg.
// ---------------------------------------------------------------------------
__global__ __launch_bounds__(256) void prep_weights(
    const float* __restrict__ g1w, const float* __restrict__ g2w,
    const float* __restrict__ g3w, const float* __restrict__ g4w,
    _Float16* __restrict__ wtf, float* __restrict__ xg) {
  __shared__ _Float16 tile[256][33];   // [k][n-local]
  const int blk = blockIdx.x;
  const int t = threadIdx.x;
  xg[blk * 256 + t] = 0.0f;            // 32 blocks x 256 = full 8192 floats

  const int l  = blk >> 3;
  const int nt = blk & 7;
  const float* src = (l == 0) ? g1w : (l == 1) ? g2w : (l == 2) ? g3w : g4w;

  // stage: coalesced global reads (128 B per 32-lane row)
  const int nn = t & 31, kb = t >> 5;   // 8 k-rows per pass
#pragma unroll 4
  for (int pass = 0; pass < 32; ++pass) {
    int kn = pass * 8 + kb;             // new k
    int ok;                             // old k
    if (l == 0) {
      if (kn < 64)        ok = kn;
      else if (kn < 192)  ok = kn + 1;
      else if (kn == 192) ok = 64;
      else if (kn == 193) ok = 193;
      else                ok = -1;
    } else {
      ok = kn;
    }
    float v = (ok >= 0) ? src[(size_t)ok * 256 + nt * 32 + nn] : 0.0f;
    tile[kn][nn] = (_Float16)v;
  }
  __syncthreads();

  // write fragments: thread t -> lane = t&63, kk = (t>>6) + 4*q
  const int lane = t & 63;
  const int nfrag = lane & 31;
  const int kbase = (lane >> 5) * 8;
  _Float16* dst = wtf + ((size_t)(l * 8 + nt) * 16) * 512;
#pragma unroll
  for (int q = 0; q < 4; ++q) {
    int kk = (t >> 6) + 4 * q;
    f16x8 fr;
#pragma unroll
    for (int j = 0; j < 8; ++j)
      fr[j] = tile[kk * 16 + kbase + j][nfrag];
    *(f16x8*)(dst + (size_t)kk * 512 + lane * 8) = fr;
  }
}

// ---------------------------------------------------------------------------
// Kernel 1: fused g-MLP (4 layers) + sum-pool for one (b, i).
// Block = 256 thr (4 waves). M=64 (j), N=256, K=256. 32x32x16 f16 MFMA.
// B-operand streamed from fragment-ordered wtf: each wave load = 1 KB contig.
// ---------------------------------------------------------------------------
__global__ __launch_bounds__(256, 4) void g_mlp_pool(
    const float* __restrict__ x_aux,          // [B, 64, 128] fp32
    const _Float16* __restrict__ wtf,         // fragment-ordered, 512 KB
    const float* __restrict__ g1b, const float* __restrict__ g2b,
    const float* __restrict__ g3b, const float* __restrict__ g4b,
    float* __restrict__ xg) {                 // [B][256] fp32 (pre-zeroed)
  __shared__ _Float16 As[64][PADK];

  const int b = blockIdx.x >> 6;
  const int i = blockIdx.x & 63;
  const int t = threadIdx.x;

  // ---- build layer-1 input tile (vectorized, coalesced) ----
  {
    const float* xb = x_aux + (size_t)b * NOBJ * 128;
    {
      const int c4 = t & 15, r0 = t >> 4;
#pragma unroll
      for (int it = 0; it < 4; ++it) {
        int r = it * 16 + r0;
        f32x4 v = *(const f32x4*)(xb + (size_t)r * 128 + c4 * 4);
        f16x4 hh = {(_Float16)v[0], (_Float16)v[1], (_Float16)v[2], (_Float16)v[3]};
        *(f16x4*)&As[r][c4 * 4] = hh;
      }
    }
    {
      const float* xi = xb + (size_t)i * 128;
      const int row = t >> 2, seg = t & 3;
#pragma unroll
      for (int u = 0; u < 4; ++u) {
        int c = seg * 32 + u * 8;
        f32x4 v0 = *(const f32x4*)(xi + c);
        f32x4 v1 = *(const f32x4*)(xi + c + 4);
        f16x8 hh = {(_Float16)v0[0], (_Float16)v0[1], (_Float16)v0[2], (_Float16)v0[3],
                    (_Float16)v1[0], (_Float16)v1[1], (_Float16)v1[2], (_Float16)v1[3]};
        *(f16x8*)&As[row][64 + c] = hh;
      }
      f16x8 z = {};
      *(f16x8*)&As[row][192 + seg * 16]     = z;
      *(f16x8*)&As[row][192 + seg * 16 + 8] = z;
      if (seg == 0) {
        As[row][192] = (_Float16)row;
        As[row][193] = (_Float16)i;
      }
    }
  }
  __syncthreads();

  const int lane = t & 63;
  const int wave = t >> 6;
  const int c31  = lane & 31;
  const int h    = lane >> 5;        // 0/1
  const int n0   = wave * 64;
  const float* gb[4] = {g1b, g2b, g3b, g4b};

  for (int layer = 0; layer < 4; ++layer) {
    const float bv0 = gb[layer][n0 + c31];
    const float bv1 = gb[layer][n0 + 32 + c31];

    f32x16 acc00 = {}, acc01 = {}, acc10 = {}, acc11 = {};

    // fragment-ordered B streams: 1 KB contiguous per wave load
    const _Float16* bp0 =
        wtf + ((size_t)(layer * 8 + wave * 2) * 16) * 512 + lane * 8;
    const _Float16* bp1 = bp0 + 16 * 512;
    const _Float16* ar0 = &As[c31][h * 8];
    const _Float16* ar1 = &As[32 + c31][h * 8];

#pragma unroll
    for (int kk = 0; kk < 16; ++kk) {
      f16x8 b0 = *(const f16x8*)(bp0 + kk * 512);
      f16x8 b1 = *(const f16x8*)(bp1 + kk * 512);
      f16x8 a0 = *(const f16x8*)(ar0 + kk * 16);
      f16x8 a1 = *(const f16x8*)(ar1 + kk * 16);
      acc00 = __builtin_amdgcn_mfma_f32_32x32x16_f16(a0, b0, acc00, 0, 0, 0);
      acc10 = __builtin_amdgcn_mfma_f32_32x32x16_f16(a1, b0, acc10, 0, 0, 0);
      acc01 = __builtin_amdgcn_mfma_f32_32x32x16_f16(a0, b1, acc01, 0, 0, 0);
      acc11 = __builtin_amdgcn_mfma_f32_32x32x16_f16(a1, b1, acc11, 0, 0, 0);
    }

    if (layer < 3) {
      __syncthreads();   // all waves done reading As
      // C/D layout: col = lane&31, row = (reg&3) + 8*(reg>>2) + 4*h
#pragma unroll
      for (int g = 0; g < 4; ++g)
#pragma unroll
        for (int r = 0; r < 4; ++r) {
          const int row = g * 8 + h * 4 + r;
          const int reg = g * 4 + r;
          As[row][n0 + c31]           = (_Float16)fmaxf(acc00[reg] + bv0, 0.f);
          As[32 + row][n0 + c31]      = (_Float16)fmaxf(acc10[reg] + bv0, 0.f);
          As[row][n0 + 32 + c31]      = (_Float16)fmaxf(acc01[reg] + bv1, 0.f);
          As[32 + row][n0 + 32 + c31] = (_Float16)fmaxf(acc11[reg] + bv1, 0.f);
        }
      __syncthreads();
    } else {
      float s0 = 0.f, s1 = 0.f;
#pragma unroll
      for (int reg = 0; reg < 16; ++reg) {
        s0 += fmaxf(acc00[reg] + bv0, 0.f) + fmaxf(acc10[reg] + bv0, 0.f);
        s1 += fmaxf(acc01[reg] + bv1, 0.f) + fmaxf(acc11[reg] + bv1, 0.f);
      }
      s0 += __shfl_xor(s0, 32, 64);
      s1 += __shfl_xor(s1, 32, 64);
      if (h == 0) {
        atomicAdd(&xg[b * 256 + n0 + c31], s0);
        atomicAdd(&xg[b * 256 + n0 + 32 + c31], s1);
      }
    }
  }
}

// ---------------------------------------------------------------------------
// Kernel 2: f-MLP. One block per batch, 1024 threads: n = t&255 owns column,
// kc = t>>8 owns a 64-wide k-chunk; LDS reduce the 4 partials per column.
// ---------------------------------------------------------------------------
__global__ __launch_bounds__(1024) void f_mlp(
    const float* __restrict__ xg,
    const float* __restrict__ f1w, const float* __restrict__ f1b,
    const float* __restrict__ f2w, const float* __restrict__ f2b,
    const float* __restrict__ f3w, const float* __restrict__ f3b,
    float* __restrict__ out) {
  __shared__ float xs[256], ys[256], ps[4][256];
  const int b = blockIdx.x;
  const int t = threadIdx.x;
  const int n = t & 255;
  const int kc = t >> 8;

  if (t < 256) xs[t] = xg[b * 256 + t];
  __syncthreads();

  float p = 0.f;
#pragma unroll 8
  for (int k0 = 0; k0 < 64; ++k0) {
    int k = kc * 64 + k0;
    p += xs[k] * f1w[k * 256 + n];
  }
  ps[kc][n] = p;
  __syncthreads();
  if (t < 256)
    ys[t] = fmaxf(f1b[t] + ps[0][t] + ps[1][t] + ps[2][t] + ps[3][t], 0.f);
  __syncthreads();

  p = 0.f;
#pragma unroll 8
  for (int k0 = 0; k0 < 64; ++k0) {
    int k = kc * 64 + k0;
    p += ys[k] * f2w[k * 256 + n];
  }
  ps[kc][n] = p;
  __syncthreads();
  if (t < 256)
    xs[t] = fmaxf(f2b[t] + ps[0][t] + ps[1][t] + ps[2][t] + ps[3][t], 0.f);
  __syncthreads();

  p = 0.f;
#pragma unroll 8
  for (int k0 = 0; k0 < 64; ++k0) {
    int k = kc * 64 + k0;
    p += xs[k] * f3w[k * 256 + n];
  }
  ps[kc][n] = p;
  __syncthreads();
  if (t < 256)
    out[b * 256 + t] = f3b[t] + ps[0][t] + ps[1][t] + ps[2][t] + ps[3][t];
}

// ---------------------------------------------------------------------------
extern "C" void kernel_launch(void* const* d_in, const int* in_sizes, int n_in,
                              void* d_out, int out_size, void* d_ws, size_t ws_size,
                              hipStream_t stream) {
  const float* x_aux = (const float*)d_in[0];
  const float* g1w = (const float*)d_in[1];
  const float* g1b = (const float*)d_in[2];
  const float* g2w = (const float*)d_in[3];
  const float* g2b = (const float*)d_in[4];
  const float* g3w = (const float*)d_in[5];
  const float* g3b = (const float*)d_in[6];
  const float* g4w = (const float*)d_in[7];
  const float* g4b = (const float*)d_in[8];
  const float* f1w = (const float*)d_in[9];
  const float* f1b = (const float*)d_in[10];
  const float* f2w = (const float*)d_in[11];
  const float* f2b = (const float*)d_in[12];
  const float* f3w = (const float*)d_in[13];
  const float* f3b = (const float*)d_in[14];
  float* out = (float*)d_out;

  _Float16* wtf = (_Float16*)d_ws;                                 // 512 KB
  float* xg = (float*)((char*)d_ws + 4u * 256u * 256u * 2u);       // 32 KB

  hipLaunchKernelGGL(prep_weights, dim3(32), dim3(256), 0, stream,
                     g1w, g2w, g3w, g4w, wtf, xg);
  hipLaunchKernelGGL(g_mlp_pool, dim3(BATCH * NOBJ), dim3(256), 0, stream,
                     x_aux, wtf, g1b, g2b, g3b, g4b, xg);
  hipLaunchKernelGGL(f_mlp, dim3(BATCH), dim3(1024), 0, stream,
                     xg, f1w, f1b, f2w, f2b, f3w, f3b, out);
}

// Round 4
// 168.908 us; speedup vs baseline: 1.5072x; 1.0307x over previous
//
#include <hip/hip_runtime.h>

#define BATCH 32
#define NOBJ  64
#define PADK  264   // halfs; A-tile row stride 528 B (16B-aligned, banks spread)

typedef _Float16 f16x4 __attribute__((ext_vector_type(4)));
typedef _Float16 f16x8 __attribute__((ext_vector_type(8)));
typedef float    f32x4 __attribute__((ext_vector_type(4)));
typedef float    f32x16 __attribute__((ext_vector_type(16)));

// ---------------------------------------------------------------------------
// Kernel 0: repack g-weights to f16 in MFMA B-FRAGMENT order:
//   wtf[l][ngrp=8][kk=16][lane=64][j=8],  value = W_l[perm_l(k)][n]
//   where n = ngrp*32 + (lane&31), k = kk*16 + (lane>>5)*8 + j.
// Layer-0 K-permutation matches the A-tile build:
//   newk [0,64)=old k (feats_j), [64,192)=old k+1 (feats_i),
//   192=old 64 (coord j), 193=old 193 (coord i), [194,256)=0.
// Grid: 32 blocks (l=blk>>3, ngrp=blk&7) x 256 threads. Also zeroes xg.
// ---------------------------------------------------------------------------
__global__ __launch_bounds__(256) void prep_weights(
    const float* __restrict__ g1w, const float* __restrict__ g2w,
    const float* __restrict__ g3w, const float* __restrict__ g4w,
    _Float16* __restrict__ wtf, float* __restrict__ xg) {
  __shared__ _Float16 tile[256][33];   // [k][n-local]
  const int blk = blockIdx.x;
  const int t = threadIdx.x;
  xg[blk * 256 + t] = 0.0f;            // 32 blocks x 256 = full 8192 floats

  const int l  = blk >> 3;
  const int nt = blk & 7;
  const float* src = (l == 0) ? g1w : (l == 1) ? g2w : (l == 2) ? g3w : g4w;

  // stage: coalesced global reads (128 B per 32-lane row)
  const int nn = t & 31, kb = t >> 5;   // 8 k-rows per pass
#pragma unroll 4
  for (int pass = 0; pass < 32; ++pass) {
    int kn = pass * 8 + kb;             // new k
    int ok;                             // old k
    if (l == 0) {
      if (kn < 64)        ok = kn;
      else if (kn < 192)  ok = kn + 1;
      else if (kn == 192) ok = 64;
      else if (kn == 193) ok = 193;
      else                ok = -1;
    } else {
      ok = kn;
    }
    float v = (ok >= 0) ? src[(size_t)ok * 256 + nt * 32 + nn] : 0.0f;
    tile[kn][nn] = (_Float16)v;
  }
  __syncthreads();

  // write fragments: thread t -> lane = t&63, kk = (t>>6) + 4*q
  const int lane = t & 63;
  const int nfrag = lane & 31;
  const int kbase = (lane >> 5) * 8;
  _Float16* dst = wtf + ((size_t)(l * 8 + nt) * 16) * 512;
#pragma unroll
  for (int q = 0; q < 4; ++q) {
    int kk = (t >> 6) + 4 * q;
    f16x8 fr;
#pragma unroll
    for (int j = 0; j < 8; ++j)
      fr[j] = tile[kk * 16 + kbase + j][nfrag];
    *(f16x8*)(dst + (size_t)kk * 512 + lane * 8) = fr;
  }
}

// ---------------------------------------------------------------------------
// Kernel 1: fused g-MLP (4 layers) + sum-pool for TWO i's per block.
// Block = 512 thr (8 waves). M=128 (2 i's x 64 j), N=256, K=256.
// Each wave: one 32-col N-group x 4 M-tiles of 32x32 (64 acc VGPRs).
// B streamed from fragment-ordered wtf: 1 KB contiguous per wave load,
// 4 MFMA per B-load (2x the round-3 ratio; halves L2 weight traffic).
// ---------------------------------------------------------------------------
__global__ __launch_bounds__(512, 4) void g_mlp_pool(
    const float* __restrict__ x_aux,          // [B, 64, 128] fp32
    const _Float16* __restrict__ wtf,         // fragment-ordered, 512 KB
    const float* __restrict__ g1b, const float* __restrict__ g2b,
    const float* __restrict__ g3b, const float* __restrict__ g4b,
    float* __restrict__ xg) {                 // [B][256] fp32 (pre-zeroed)
  __shared__ _Float16 As[128][PADK];          // 67.6 KB -> 2 blocks/CU

  const int b  = blockIdx.x >> 5;
  const int i0 = (blockIdx.x & 31) * 2;
  const int t  = threadIdx.x;

  // ---- build layer-1 input tile (vectorized, coalesced) ----
  {
    const float* xb = x_aux + (size_t)b * NOBJ * 128;
    // part 1: cols [0,64) = x_aux[b][r&63][0:64]
    {
      const int c4 = t & 15, r0 = t >> 4;     // 32 rows / pass
#pragma unroll
      for (int it = 0; it < 4; ++it) {
        int r = it * 32 + r0;
        f32x4 v = *(const f32x4*)(xb + (size_t)(r & 63) * 128 + c4 * 4);
        f16x4 hh = {(_Float16)v[0], (_Float16)v[1], (_Float16)v[2], (_Float16)v[3]};
        *(f16x4*)&As[r][c4 * 4] = hh;
      }
    }
    // part 2: cols [64,192) = x_aux[b][i0 + (row>>6)][0:128]
    // part 3: cols [192,256) = zeros + coords at 192 (=j), 193 (=i)
    {
      const int row = t >> 2, seg = t & 3;    // rows 0..127
      const int ir = i0 + (row >> 6);
      const float* xi = xb + (size_t)ir * 128;
#pragma unroll
      for (int u = 0; u < 4; ++u) {
        int c = seg * 32 + u * 8;
        f32x4 v0 = *(const f32x4*)(xi + c);
        f32x4 v1 = *(const f32x4*)(xi + c + 4);
        f16x8 hh = {(_Float16)v0[0], (_Float16)v0[1], (_Float16)v0[2], (_Float16)v0[3],
                    (_Float16)v1[0], (_Float16)v1[1], (_Float16)v1[2], (_Float16)v1[3]};
        *(f16x8*)&As[row][64 + c] = hh;
      }
      f16x8 z = {};
      *(f16x8*)&As[row][192 + seg * 16]     = z;
      *(f16x8*)&As[row][192 + seg * 16 + 8] = z;
      if (seg == 0) {
        As[row][192] = (_Float16)(row & 63);
        As[row][193] = (_Float16)ir;
      }
    }
  }
  __syncthreads();

  const int lane = t & 63;
  const int wave = t >> 6;          // 0..7 = N-group
  const int c31  = lane & 31;
  const int h    = lane >> 5;       // 0/1
  const int n0   = wave * 32;
  const float* gb[4] = {g1b, g2b, g3b, g4b};

  for (int layer = 0; layer < 4; ++layer) {
    const float bv = gb[layer][n0 + c31];

    f32x16 acc0 = {}, acc1 = {}, acc2 = {}, acc3 = {};

    const _Float16* bp =
        wtf + ((size_t)(layer * 8 + wave) * 16) * 512 + lane * 8;
    const _Float16* ar0 = &As[c31][h * 8];
    const _Float16* ar1 = &As[32 + c31][h * 8];
    const _Float16* ar2 = &As[64 + c31][h * 8];
    const _Float16* ar3 = &As[96 + c31][h * 8];

#pragma unroll
    for (int kk = 0; kk < 16; ++kk) {
      f16x8 bfr = *(const f16x8*)(bp + kk * 512);
      f16x8 a0 = *(const f16x8*)(ar0 + kk * 16);
      f16x8 a1 = *(const f16x8*)(ar1 + kk * 16);
      f16x8 a2 = *(const f16x8*)(ar2 + kk * 16);
      f16x8 a3 = *(const f16x8*)(ar3 + kk * 16);
      acc0 = __builtin_amdgcn_mfma_f32_32x32x16_f16(a0, bfr, acc0, 0, 0, 0);
      acc1 = __builtin_amdgcn_mfma_f32_32x32x16_f16(a1, bfr, acc1, 0, 0, 0);
      acc2 = __builtin_amdgcn_mfma_f32_32x32x16_f16(a2, bfr, acc2, 0, 0, 0);
      acc3 = __builtin_amdgcn_mfma_f32_32x32x16_f16(a3, bfr, acc3, 0, 0, 0);
    }

    if (layer < 3) {
      __syncthreads();   // all waves done reading As
      // C/D layout: col = lane&31, row = (reg&3) + 8*(reg>>2) + 4*h
#pragma unroll
      for (int g = 0; g < 4; ++g)
#pragma unroll
        for (int r = 0; r < 4; ++r) {
          const int row = g * 8 + h * 4 + r;
          const int reg = g * 4 + r;
          As[row][n0 + c31]      = (_Float16)fmaxf(acc0[reg] + bv, 0.f);
          As[32 + row][n0 + c31] = (_Float16)fmaxf(acc1[reg] + bv, 0.f);
          As[64 + row][n0 + c31] = (_Float16)fmaxf(acc2[reg] + bv, 0.f);
          As[96 + row][n0 + c31] = (_Float16)fmaxf(acc3[reg] + bv, 0.f);
        }
      __syncthreads();
    } else {
      // layer 4: bias + relu + pool over all 128 rows (both i's)
      float s = 0.f;
#pragma unroll
      for (int reg = 0; reg < 16; ++reg) {
        s += fmaxf(acc0[reg] + bv, 0.f) + fmaxf(acc1[reg] + bv, 0.f)
           + fmaxf(acc2[reg] + bv, 0.f) + fmaxf(acc3[reg] + bv, 0.f);
      }
      s += __shfl_xor(s, 32, 64);   // combine h=0/h=1 row halves
      if (h == 0)
        atomicAdd(&xg[b * 256 + n0 + c31], s);
    }
  }
}

// ---------------------------------------------------------------------------
// Kernel 2: f-MLP. One block per batch, 1024 threads: n = t&255 owns column,
// kc = t>>8 owns a 64-wide k-chunk; LDS reduce the 4 partials per column.
// ---------------------------------------------------------------------------
__global__ __launch_bounds__(1024) void f_mlp(
    const float* __restrict__ xg,
    const float* __restrict__ f1w, const float* __restrict__ f1b,
    const float* __restrict__ f2w, const float* __restrict__ f2b,
    const float* __restrict__ f3w, const float* __restrict__ f3b,
    float* __restrict__ out) {
  __shared__ float xs[256], ys[256], ps[4][256];
  const int b = blockIdx.x;
  const int t = threadIdx.x;
  const int n = t & 255;
  const int kc = t >> 8;

  if (t < 256) xs[t] = xg[b * 256 + t];
  __syncthreads();

  float p = 0.f;
#pragma unroll 8
  for (int k0 = 0; k0 < 64; ++k0) {
    int k = kc * 64 + k0;
    p += xs[k] * f1w[k * 256 + n];
  }
  ps[kc][n] = p;
  __syncthreads();
  if (t < 256)
    ys[t] = fmaxf(f1b[t] + ps[0][t] + ps[1][t] + ps[2][t] + ps[3][t], 0.f);
  __syncthreads();

  p = 0.f;
#pragma unroll 8
  for (int k0 = 0; k0 < 64; ++k0) {
    int k = kc * 64 + k0;
    p += ys[k] * f2w[k * 256 + n];
  }
  ps[kc][n] = p;
  __syncthreads();
  if (t < 256)
    xs[t] = fmaxf(f2b[t] + ps[0][t] + ps[1][t] + ps[2][t] + ps[3][t], 0.f);
  __syncthreads();

  p = 0.f;
#pragma unroll 8
  for (int k0 = 0; k0 < 64; ++k0) {
    int k = kc * 64 + k0;
    p += xs[k] * f3w[k * 256 + n];
  }
  ps[kc][n] = p;
  __syncthreads();
  if (t < 256)
    out[b * 256 + t] = f3b[t] + ps[0][t] + ps[1][t] + ps[2][t] + ps[3][t];
}

// ---------------------------------------------------------------------------
extern "C" void kernel_launch(void* const* d_in, const int* in_sizes, int n_in,
                              void* d_out, int out_size, void* d_ws, size_t ws_size,
                              hipStream_t stream) {
  const float* x_aux = (const float*)d_in[0];
  const float* g1w = (const float*)d_in[1];
  const float* g1b = (const float*)d_in[2];
  const float* g2w = (const float*)d_in[3];
  const float* g2b = (const float*)d_in[4];
  const float* g3w = (const float*)d_in[5];
  const float* g3b = (const float*)d_in[6];
  const float* g4w = (const float*)d_in[7];
  const float* g4b = (const float*)d_in[8];
  const float* f1w = (const float*)d_in[9];
  const float* f1b = (const float*)d_in[10];
  const float* f2w = (const float*)d_in[11];
  const float* f2b = (const float*)d_in[12];
  const float* f3w = (const float*)d_in[13];
  const float* f3b = (const float*)d_in[14];
  float* out = (float*)d_out;

  _Float16* wtf = (_Float16*)d_ws;                                 // 512 KB
  float* xg = (float*)((char*)d_ws + 4u * 256u * 256u * 2u);       // 32 KB

  hipLaunchKernelGGL(prep_weights, dim3(32), dim3(256), 0, stream,
                     g1w, g2w, g3w, g4w, wtf, xg);
  hipLaunchKernelGGL(g_mlp_pool, dim3(BATCH * 32), dim3(512), 0, stream,
                     x_aux, wtf, g1b, g2b, g3b, g4b, xg);
  hipLaunchKernelGGL(f_mlp, dim3(BATCH), dim3(1024), 0, stream,
                     xg, f1w, f1b, f2w, f2b, f3w, f3b, out);
}